// Round 3
// baseline (326.289 us; speedup 1.0000x reference)
//
#include <hip/hip_runtime.h>
#include <hip/hip_bf16.h>

// SDPA, causal, b=16 t=2048 d=64. Outputs FP32: d_out = [ out | sm_qk ].
// One wave per 16 q-rows. Two-phase: (1) row sums of exp(S), (2) recompute S,
// write P=exp(S)/l fp32, accumulate O=P*V via bf16 MFMA.
// QK^T uses split-bf16 compensation: q*k ~= qh*kh + qh*kl + ql*kh (err ~1e-3).

#define BATCHES 16
#define SEQ 2048
#define DIM 64
#define QROWS 16
#define KT 32
#define NQB (SEQ / QROWS) /* 128 */
#define PLD 40            /* bf16 P-tile LDS stride */

typedef __attribute__((ext_vector_type(8))) short bf16x8;
typedef __attribute__((ext_vector_type(4))) float f32x4;

static __device__ __forceinline__ short f2bf(float f) {
    return __builtin_bit_cast(short, __float2bfloat16(f));
}
static __device__ __forceinline__ float bf2f(short s) {
    unsigned int u = ((unsigned int)(unsigned short)s) << 16;
    return __builtin_bit_cast(float, u);
}
// split 8 consecutive fp32 (scaled) into hi/lo bf16 fragments
static __device__ __forceinline__ void split8(f32x4 a, f32x4 b, float sc,
                                              bf16x8& h, bf16x8& l) {
#pragma unroll
    for (int e = 0; e < 4; ++e) {
        float x = a[e] * sc;
        short hb = f2bf(x);
        h[e] = hb; l[e] = f2bf(x - bf2f(hb));
    }
#pragma unroll
    for (int e = 0; e < 4; ++e) {
        float x = b[e] * sc;
        short hb = f2bf(x);
        h[4 + e] = hb; l[4 + e] = f2bf(x - bf2f(hb));
    }
}

__global__ __launch_bounds__(64) void sdpa_pass1(
    const float* __restrict__ Qg, const float* __restrict__ Kg,
    const float* __restrict__ Vg, float* __restrict__ Og, float* __restrict__ Pg)
{
    const int qb = blockIdx.x;        // 0..127
    const int b  = blockIdx.y;        // 0..15
    const int q0 = qb * QROWS;
    const int lane = threadIdx.x;     // one wave
    const int lo = lane & 15;
    const int hi = lane >> 4;

    __shared__ short Pl[QROWS * PLD]; // bf16 P tile for the PV A-fragment

    const float* qB = Qg + (size_t)b * SEQ * DIM;
    const float* kB = Kg + (size_t)b * SEQ * DIM;
    const float* vB = Vg + (size_t)b * SEQ * DIM;

    // Q A-frags (row=lo, k=hi*8+e), scaled by 1/8, hi/lo split
    bf16x8 qa0h, qa0l, qa1h, qa1l;
    {
        const float* qr = &qB[(size_t)(q0 + lo) * DIM + hi * 8];
        split8(*(const f32x4*)qr,        *(const f32x4*)(qr + 4),  0.125f, qa0h, qa0l);
        split8(*(const f32x4*)(qr + 32), *(const f32x4*)(qr + 36), 0.125f, qa1h, qa1l);
    }

    const int nkt = (q0 >> 5) + 1;    // K-tiles with any unmasked column
    float rl[4] = {0.f, 0.f, 0.f, 0.f};

    // ---------------- phase 1: l = sum exp(S) per row ----------------
    for (int kt = 0; kt < nkt; ++kt) {
        const int kvb = kt * KT;
#pragma unroll
        for (int h = 0; h < 2; ++h) {
            const float* kr = &kB[(size_t)(kvb + h * 16 + lo) * DIM + hi * 8];
            bf16x8 kh0, kl0, kh1, kl1;
            split8(*(const f32x4*)kr,        *(const f32x4*)(kr + 4),  1.f, kh0, kl0);
            split8(*(const f32x4*)(kr + 32), *(const f32x4*)(kr + 36), 1.f, kh1, kl1);
            f32x4 acc = {0.f, 0.f, 0.f, 0.f};
            acc = __builtin_amdgcn_mfma_f32_16x16x32_bf16(qa0h, kh0, acc, 0, 0, 0);
            acc = __builtin_amdgcn_mfma_f32_16x16x32_bf16(qa1h, kh1, acc, 0, 0, 0);
            acc = __builtin_amdgcn_mfma_f32_16x16x32_bf16(qa0h, kl0, acc, 0, 0, 0);
            acc = __builtin_amdgcn_mfma_f32_16x16x32_bf16(qa1h, kl1, acc, 0, 0, 0);
            acc = __builtin_amdgcn_mfma_f32_16x16x32_bf16(qa0l, kh0, acc, 0, 0, 0);
            acc = __builtin_amdgcn_mfma_f32_16x16x32_bf16(qa1l, kh1, acc, 0, 0, 0);
            const int kv = kvb + h * 16 + lo;
#pragma unroll
            for (int j = 0; j < 4; ++j)
                if (kv <= q0 + hi * 4 + j) rl[j] += __expf(acc[j]);
        }
    }
#pragma unroll
    for (int m = 1; m <= 8; m <<= 1)
#pragma unroll
        for (int j = 0; j < 4; ++j) rl[j] += __shfl_xor(rl[j], m, 16);
    float il[4];
#pragma unroll
    for (int j = 0; j < 4; ++j) il[j] = 1.0f / rl[j];

    // ------------- phase 2: P = exp(S)/l (fp32 out) + O = P*V -------------
    f32x4 o[4];
#pragma unroll
    for (int n = 0; n < 4; ++n) { o[n][0] = 0.f; o[n][1] = 0.f; o[n][2] = 0.f; o[n][3] = 0.f; }

    for (int kt = 0; kt < nkt; ++kt) {
        const int kvb = kt * KT;
#pragma unroll
        for (int h = 0; h < 2; ++h) {
            const float* kr = &kB[(size_t)(kvb + h * 16 + lo) * DIM + hi * 8];
            bf16x8 kh0, kl0, kh1, kl1;
            split8(*(const f32x4*)kr,        *(const f32x4*)(kr + 4),  1.f, kh0, kl0);
            split8(*(const f32x4*)(kr + 32), *(const f32x4*)(kr + 36), 1.f, kh1, kl1);
            f32x4 acc = {0.f, 0.f, 0.f, 0.f};
            acc = __builtin_amdgcn_mfma_f32_16x16x32_bf16(qa0h, kh0, acc, 0, 0, 0);
            acc = __builtin_amdgcn_mfma_f32_16x16x32_bf16(qa1h, kh1, acc, 0, 0, 0);
            acc = __builtin_amdgcn_mfma_f32_16x16x32_bf16(qa0h, kl0, acc, 0, 0, 0);
            acc = __builtin_amdgcn_mfma_f32_16x16x32_bf16(qa1h, kl1, acc, 0, 0, 0);
            acc = __builtin_amdgcn_mfma_f32_16x16x32_bf16(qa0l, kh0, acc, 0, 0, 0);
            acc = __builtin_amdgcn_mfma_f32_16x16x32_bf16(qa1l, kh1, acc, 0, 0, 0);
            const int kv = kvb + h * 16 + lo;
#pragma unroll
            for (int j = 0; j < 4; ++j) {
                const float p = (kv <= q0 + hi * 4 + j) ? __expf(acc[j]) * il[j] : 0.f;
                Pg[((size_t)(b * SEQ) + q0 + hi * 4 + j) * SEQ + kv] = p;   // fp32
                Pl[(hi * 4 + j) * PLD + h * 16 + lo] = f2bf(p);
            }
        }
        // PV: A-frag of (normalized) P from LDS; B-frag of V from global
        const bf16x8 pa = *(const bf16x8*)&Pl[lo * PLD + hi * 8];
#pragma unroll
        for (int n = 0; n < 4; ++n) {
            bf16x8 vb;
#pragma unroll
            for (int e = 0; e < 8; ++e)
                vb[e] = f2bf(vB[(size_t)(kvb + hi * 8 + e) * DIM + n * 16 + lo]);
            o[n] = __builtin_amdgcn_mfma_f32_16x16x32_bf16(pa, vb, o[n], 0, 0, 0);
        }
    }

    // ---- zero-fill fully-masked columns (exact 0 == ref underflow) ----
    {
        const int r = lane >> 2;
        float* rowp = &Pg[((size_t)(b * SEQ) + q0 + r) * SEQ];
        const f32x4 z = {0.f, 0.f, 0.f, 0.f};
        for (int c0 = nkt * KT + (lane & 3) * 8; c0 < SEQ; c0 += KT) {
            *(f32x4*)&rowp[c0] = z;
            *(f32x4*)&rowp[c0 + 4] = z;
        }
    }
    // ---- O (already normalized: P in PV was exp/l), fp32 ----
    {
        float* og = &Og[((size_t)(b * SEQ) + q0 + hi * 4) * DIM + lo];
#pragma unroll
        for (int j = 0; j < 4; ++j)
#pragma unroll
            for (int n = 0; n < 4; ++n)
                og[j * DIM + n * 16] = o[n][j];
    }
}

extern "C" void kernel_launch(void* const* d_in, const int* in_sizes, int n_in,
                              void* d_out, int out_size, void* d_ws, size_t ws_size,
                              hipStream_t stream) {
    const float* q = (const float*)d_in[0];
    const float* k = (const float*)d_in[1];
    const float* v = (const float*)d_in[2];
    float* out  = (float*)d_out;                        // [B,T,D] fp32
    float* smqk = out + (size_t)BATCHES * SEQ * DIM;    // [B,T,T] fp32

    dim3 g1(NQB, BATCHES);
    sdpa_pass1<<<g1, 64, 0, stream>>>(q, k, v, out, smqk);
}

// Round 4
// 189.347 us; speedup vs baseline: 1.7232x; 1.7232x over previous
//
#include <hip/hip_runtime.h>
#include <hip/hip_bf16.h>

// SDPA, causal, b=16 t=2048 d=64. Outputs FP32: d_out = [ out | sm_qk ].
// 4 waves/block, QB=64 q-rows. Two-phase (rowsum, then recompute+emit).
// K staged pre-split (hi/lo bf16) in LDS, shared by 4 waves; V staged
// transposed bf16 in LDS; P tile fp32 in LDS for coalesced global writes.
// QK^T split-bf16 compensation: q*k ~= qh*kh + qh*kl + ql*kh.

#define BATCHES 16
#define SEQ 2048
#define DIM 64
#define QB 64
#define KT 64
#define NQB (SEQ / QB) /* 32 */
#define KLD 72   /* K LDS row stride, shorts (144B) */
#define VLD 72   /* V^T LDS row stride, shorts */
#define PFLD 68  /* P LDS row stride, floats (272B) */

typedef __attribute__((ext_vector_type(8))) short bf16x8;
typedef __attribute__((ext_vector_type(4))) short short4v;
typedef __attribute__((ext_vector_type(4))) float f32x4;

static __device__ __forceinline__ short f2bf(float f) {
    return __builtin_bit_cast(short, __float2bfloat16(f));
}
static __device__ __forceinline__ float bf2f(short s) {
    unsigned int u = ((unsigned int)(unsigned short)s) << 16;
    return __builtin_bit_cast(float, u);
}
static __device__ __forceinline__ void split8(f32x4 a, f32x4 b, float sc,
                                              bf16x8& h, bf16x8& l) {
#pragma unroll
    for (int e = 0; e < 4; ++e) {
        float x = a[e] * sc;
        short hb = f2bf(x);
        h[e] = hb; l[e] = f2bf(x - bf2f(hb));
    }
#pragma unroll
    for (int e = 0; e < 4; ++e) {
        float x = b[e] * sc;
        short hb = f2bf(x);
        h[4 + e] = hb; l[4 + e] = f2bf(x - bf2f(hb));
    }
}

__global__ __launch_bounds__(256, 3) void sdpa_fused(
    const float* __restrict__ Qg, const float* __restrict__ Kg,
    const float* __restrict__ Vg, float* __restrict__ Og, float* __restrict__ Pg)
{
    const int x = blockIdx.x;           // 0..31
    const int b = blockIdx.y;           // 0..15
    // complementary pairing across the two dispatch rounds (y and y+8 land
    // on the same CU slot): uniformizes causal work per CU
    const int qb = ((b >> 3) & 1) ? (NQB - 1 - x) : x;
    const int q0 = qb * QB;

    const int tid = threadIdx.x;
    const int lane = tid & 63;
    const int wave = tid >> 6;          // wave owns q-rows [wave*16, wave*16+16)
    const int lo = lane & 15;
    const int hi = lane >> 4;

    __shared__ short Khi[KT * KLD];     // K tile hi-bf16, [k][d]
    __shared__ short Klo[KT * KLD];     // K tile lo-bf16 (residual)
    __shared__ short Vt[DIM * VLD];     // V tile transposed bf16, [d][k]
    __shared__ float Pf[QB * PFLD];     // P tile fp32, [row][col]

    const float* qB = Qg + (size_t)b * SEQ * DIM;
    const float* kB = Kg + (size_t)b * SEQ * DIM;
    const float* vB = Vg + (size_t)b * SEQ * DIM;

    // ---- Q A-frags (row=lo of own band, k=hi*8+e), scale 1/8, hi/lo split
    bf16x8 qa0h, qa0l, qa1h, qa1l;
    {
        const float* qr = &qB[(size_t)(q0 + wave * 16 + lo) * DIM + hi * 8];
        split8(*(const f32x4*)qr,        *(const f32x4*)(qr + 4),  0.125f, qa0h, qa0l);
        split8(*(const f32x4*)(qr + 32), *(const f32x4*)(qr + 36), 0.125f, qa1h, qa1l);
    }

    const int nkt = qb + 1;             // K-tiles with any unmasked column
    float rl[4] = {0.f, 0.f, 0.f, 0.f};

    // ================ phase 1: l = sum exp(S) per row ================
    for (int kt = 0; kt < nkt; ++kt) {
        __syncthreads();
        {   // stage K tile, pre-split hi/lo
            const int r = tid >> 4;
            const int c = (tid & 15) * 4;
#pragma unroll
            for (int i = 0; i < 4; ++i) {
                const int rr = r + 16 * i;
                f32x4 f = *(const f32x4*)&kB[(size_t)(kt * KT + rr) * DIM + c];
                short4v hh, ll;
#pragma unroll
                for (int e = 0; e < 4; ++e) {
                    short hb = f2bf(f[e]);
                    hh[e] = hb; ll[e] = f2bf(f[e] - bf2f(hb));
                }
                *(short4v*)&Khi[rr * KLD + c] = hh;
                *(short4v*)&Klo[rr * KLD + c] = ll;
            }
        }
        __syncthreads();
        const int nmax = (kt == qb) ? (wave + 1) : 4;  // skip fully-masked n
        for (int n = 0; n < nmax; ++n) {
            bf16x8 kh0 = *(const bf16x8*)&Khi[(16 * n + lo) * KLD + hi * 8];
            bf16x8 kh1 = *(const bf16x8*)&Khi[(16 * n + lo) * KLD + 32 + hi * 8];
            bf16x8 kl0 = *(const bf16x8*)&Klo[(16 * n + lo) * KLD + hi * 8];
            bf16x8 kl1 = *(const bf16x8*)&Klo[(16 * n + lo) * KLD + 32 + hi * 8];
            f32x4 acc = {0.f, 0.f, 0.f, 0.f};
            acc = __builtin_amdgcn_mfma_f32_16x16x32_bf16(qa0h, kh0, acc, 0, 0, 0);
            acc = __builtin_amdgcn_mfma_f32_16x16x32_bf16(qa1h, kh1, acc, 0, 0, 0);
            acc = __builtin_amdgcn_mfma_f32_16x16x32_bf16(qa0h, kl0, acc, 0, 0, 0);
            acc = __builtin_amdgcn_mfma_f32_16x16x32_bf16(qa1h, kl1, acc, 0, 0, 0);
            acc = __builtin_amdgcn_mfma_f32_16x16x32_bf16(qa0l, kh0, acc, 0, 0, 0);
            acc = __builtin_amdgcn_mfma_f32_16x16x32_bf16(qa1l, kh1, acc, 0, 0, 0);
            if (kt < qb) {
#pragma unroll
                for (int j = 0; j < 4; ++j) rl[j] += __expf(acc[j]);
            } else {
                const int col = 16 * n + lo;
#pragma unroll
                for (int j = 0; j < 4; ++j)
                    if (col <= wave * 16 + hi * 4 + j) rl[j] += __expf(acc[j]);
            }
        }
    }
#pragma unroll
    for (int m = 1; m <= 8; m <<= 1)
#pragma unroll
        for (int j = 0; j < 4; ++j) rl[j] += __shfl_xor(rl[j], m, 16);
    float il[4];
#pragma unroll
    for (int j = 0; j < 4; ++j) il[j] = 1.0f / rl[j];

    // ============ phase 2: P = exp(S)/l (fp32) + O = P*V ============
    f32x4 o[4];
#pragma unroll
    for (int n = 0; n < 4; ++n) { o[n][0] = 0.f; o[n][1] = 0.f; o[n][2] = 0.f; o[n][3] = 0.f; }

    for (int kt = 0; kt < nkt; ++kt) {
        __syncthreads();
        {   // stage K (split) and V (transposed)
            const int r = tid >> 4;
            const int c = (tid & 15) * 4;
#pragma unroll
            for (int i = 0; i < 4; ++i) {
                const int rr = r + 16 * i;
                f32x4 f = *(const f32x4*)&kB[(size_t)(kt * KT + rr) * DIM + c];
                short4v hh, ll;
#pragma unroll
                for (int e = 0; e < 4; ++e) {
                    short hb = f2bf(f[e]);
                    hh[e] = hb; ll[e] = f2bf(f[e] - bf2f(hb));
                }
                *(short4v*)&Khi[rr * KLD + c] = hh;
                *(short4v*)&Klo[rr * KLD + c] = ll;
                f32x4 g = *(const f32x4*)&vB[(size_t)(kt * KT + rr) * DIM + c];
#pragma unroll
                for (int e = 0; e < 4; ++e)
                    Vt[(c + e) * VLD + rr] = f2bf(g[e]);
            }
        }
        __syncthreads();
        // S = QK^T (compensated), P into fp32 LDS tile
#pragma unroll
        for (int n = 0; n < 4; ++n) {
            const bool fm = (kt == qb) && (n > wave);  // wave-uniform
            f32x4 acc = {0.f, 0.f, 0.f, 0.f};
            if (!fm) {
                bf16x8 kh0 = *(const bf16x8*)&Khi[(16 * n + lo) * KLD + hi * 8];
                bf16x8 kh1 = *(const bf16x8*)&Khi[(16 * n + lo) * KLD + 32 + hi * 8];
                bf16x8 kl0 = *(const bf16x8*)&Klo[(16 * n + lo) * KLD + hi * 8];
                bf16x8 kl1 = *(const bf16x8*)&Klo[(16 * n + lo) * KLD + 32 + hi * 8];
                acc = __builtin_amdgcn_mfma_f32_16x16x32_bf16(qa0h, kh0, acc, 0, 0, 0);
                acc = __builtin_amdgcn_mfma_f32_16x16x32_bf16(qa1h, kh1, acc, 0, 0, 0);
                acc = __builtin_amdgcn_mfma_f32_16x16x32_bf16(qa0h, kl0, acc, 0, 0, 0);
                acc = __builtin_amdgcn_mfma_f32_16x16x32_bf16(qa1h, kl1, acc, 0, 0, 0);
                acc = __builtin_amdgcn_mfma_f32_16x16x32_bf16(qa0l, kh0, acc, 0, 0, 0);
                acc = __builtin_amdgcn_mfma_f32_16x16x32_bf16(qa1l, kh1, acc, 0, 0, 0);
            }
            const int col = 16 * n + lo;
#pragma unroll
            for (int j = 0; j < 4; ++j) {
                const int row = wave * 16 + hi * 4 + j;
                const float p = (!fm && (kt < qb || col <= row)) ? __expf(acc[j]) * il[j] : 0.f;
                Pf[row * PFLD + col] = p;
            }
        }
        // PV: A-frag from own Pf band (fp32->bf16), B-frag from Vt
        {
            const float* pr = &Pf[(wave * 16 + lo) * PFLD + hi * 8];
            bf16x8 pa0, pa1;
            {
                f32x4 a = *(const f32x4*)pr, c2 = *(const f32x4*)(pr + 4);
                f32x4 d = *(const f32x4*)(pr + 32), e2 = *(const f32x4*)(pr + 36);
#pragma unroll
                for (int e = 0; e < 4; ++e) {
                    pa0[e] = f2bf(a[e]); pa0[4 + e] = f2bf(c2[e]);
                    pa1[e] = f2bf(d[e]); pa1[4 + e] = f2bf(e2[e]);
                }
            }
#pragma unroll
            for (int n = 0; n < 4; ++n) {
                bf16x8 vb0 = *(const bf16x8*)&Vt[(16 * n + lo) * VLD + hi * 8];
                bf16x8 vb1 = *(const bf16x8*)&Vt[(16 * n + lo) * VLD + 32 + hi * 8];
                o[n] = __builtin_amdgcn_mfma_f32_16x16x32_bf16(pa0, vb0, o[n], 0, 0, 0);
                o[n] = __builtin_amdgcn_mfma_f32_16x16x32_bf16(pa1, vb1, o[n], 0, 0, 0);
            }
        }
        // stream own P band to global: coalesced 256B row bursts
        {
            const int r = wave * 16 + (lane >> 2);
            const int cb = (lane & 3) * 16;
            float* dst = &Pg[((size_t)(b * SEQ) + q0 + r) * SEQ + kt * KT + cb];
            const float* src = &Pf[r * PFLD + cb];
#pragma unroll
            for (int i = 0; i < 4; ++i)
                *(f32x4*)&dst[4 * i] = *(const f32x4*)&src[4 * i];
        }
    }

    // ---- zero-fill fully-masked column tiles (exact 0 == ref underflow) ----
    {
        const int r = tid >> 2;
        float* rowp = &Pg[((size_t)(b * SEQ) + q0 + r) * SEQ];
        const f32x4 z = {0.f, 0.f, 0.f, 0.f};
        for (int cb = nkt * KT + (tid & 3) * 16; cb < SEQ; cb += KT)
#pragma unroll
            for (int i = 0; i < 4; ++i)
                *(f32x4*)&rowp[cb + 4 * i] = z;
    }
    // ---- O (already normalized), fp32 ----
    {
        float* og = &Og[((size_t)(b * SEQ) + q0 + wave * 16 + hi * 4) * DIM + lo];
#pragma unroll
        for (int j = 0; j < 4; ++j)
#pragma unroll
            for (int n = 0; n < 4; ++n)
                og[j * DIM + n * 16] = o[n][j];
    }
}

extern "C" void kernel_launch(void* const* d_in, const int* in_sizes, int n_in,
                              void* d_out, int out_size, void* d_ws, size_t ws_size,
                              hipStream_t stream) {
    const float* q = (const float*)d_in[0];
    const float* k = (const float*)d_in[1];
    const float* v = (const float*)d_in[2];
    float* out  = (float*)d_out;                        // [B,T,D] fp32
    float* smqk = out + (size_t)BATCHES * SEQ * DIM;    // [B,T,T] fp32

    dim3 grid(NQB, BATCHES);
    sdpa_fused<<<grid, 256, 0, stream>>>(q, k, v, out, smqk);
}

// Round 5
// 122.103 us; speedup vs baseline: 2.6722x; 1.5507x over previous
//
#include <hip/hip_runtime.h>
#include <hip/hip_bf16.h>

// SDPA, causal, b=16 t=2048 d=64. Outputs FP32: d_out = [ out | sm_qk ].
// 4 waves/block, QB=64. Two-phase (rowsum; recompute+emit).
// R5: (a) register-prefetch double-buffer of K/V staging (T14) so global
// latency hides under compute; (b) XCD batch-clustering: block i -> XCD i%8,
// each XCD owns 2 batches => K/V L2-resident; (c) phase-1 uncompensated QK^T
// (l error ~0.3%); phase 2 keeps split-bf16 compensation for emitted P.

#define BATCHES 16
#define SEQ 2048
#define DIM 64
#define QB 64
#define KT 64
#define NQB (SEQ / QB) /* 32 */
#define KLD 72   /* K LDS row stride, shorts */
#define VLD 72   /* V^T LDS row stride, shorts */
#define PFLD 68  /* P LDS row stride, floats */

typedef __attribute__((ext_vector_type(8))) short bf16x8;
typedef __attribute__((ext_vector_type(4))) short short4v;
typedef __attribute__((ext_vector_type(4))) float f32x4;

static __device__ __forceinline__ short f2bf(float f) {
    return __builtin_bit_cast(short, __float2bfloat16(f));
}
static __device__ __forceinline__ float bf2f(short s) {
    unsigned int u = ((unsigned int)(unsigned short)s) << 16;
    return __builtin_bit_cast(float, u);
}
static __device__ __forceinline__ void split8(f32x4 a, f32x4 b, float sc,
                                              bf16x8& h, bf16x8& l) {
#pragma unroll
    for (int e = 0; e < 4; ++e) {
        float x = a[e] * sc;
        short hb = f2bf(x);
        h[e] = hb; l[e] = f2bf(x - bf2f(hb));
    }
#pragma unroll
    for (int e = 0; e < 4; ++e) {
        float x = b[e] * sc;
        short hb = f2bf(x);
        h[4 + e] = hb; l[4 + e] = f2bf(x - bf2f(hb));
    }
}

__global__ __launch_bounds__(256, 3) void sdpa_fused(
    const float* __restrict__ Qg, const float* __restrict__ Kg,
    const float* __restrict__ Vg, float* __restrict__ Og, float* __restrict__ Pg)
{
    // 1D grid 512. XCD = i%8 (round-robin dispatch). XCD g owns batches
    // {2g, 2g+1}; CU pairing (qb=c, b=2g)+(qb=31-c, b=2g+1) balances causal work.
    const int i = blockIdx.x;
    const int g = i & 7;
    const int j = i >> 3;             // 0..63
    const int b = 2 * g + (j >> 5);
    const int jj = j & 31;
    const int qb = (j < 32) ? jj : (31 - jj);
    const int q0 = qb * QB;

    const int tid = threadIdx.x;
    const int lane = tid & 63;
    const int wave = tid >> 6;        // wave owns q-rows [wave*16, wave*16+16)
    const int lo = lane & 15;
    const int hi = lane >> 4;
    const int sr = tid >> 4;          // stage row base (K): rows sr+16*ii
    const int sc = (tid & 15) * 4;    // stage col
    const int vr = (tid >> 4) * 4;    // stage rows (V): vr..vr+3

    __shared__ short Khi[KT * KLD];
    __shared__ short Klo[KT * KLD];
    __shared__ short Vt[DIM * VLD];
    __shared__ float Pf[QB * PFLD];

    const float* qB = Qg + (size_t)b * SEQ * DIM;
    const float* kB = Kg + (size_t)b * SEQ * DIM;
    const float* vB = Vg + (size_t)b * SEQ * DIM;

    // Q A-frags, scale 1/8, hi/lo split
    bf16x8 qa0h, qa0l, qa1h, qa1l;
    {
        const float* qr = &qB[(size_t)(q0 + wave * 16 + lo) * DIM + hi * 8];
        split8(*(const f32x4*)qr,        *(const f32x4*)(qr + 4),  0.125f, qa0h, qa0l);
        split8(*(const f32x4*)(qr + 32), *(const f32x4*)(qr + 36), 0.125f, qa1h, qa1l);
    }

    const int nkt = qb + 1;
    float rl[4] = {0.f, 0.f, 0.f, 0.f};

    // ================ phase 1: l = sum exp(S) (uncompensated) ================
    f32x4 kpre[4];
#pragma unroll
    for (int ii = 0; ii < 4; ++ii)
        kpre[ii] = *(const f32x4*)&kB[(size_t)(sr + 16 * ii) * DIM + sc];

    for (int kt = 0; kt < nkt; ++kt) {
        __syncthreads();                       // prev readers done with Khi
#pragma unroll
        for (int ii = 0; ii < 4; ++ii) {
            short4v hh;
#pragma unroll
            for (int e = 0; e < 4; ++e) hh[e] = f2bf(kpre[ii][e]);
            *(short4v*)&Khi[(sr + 16 * ii) * KLD + sc] = hh;
        }
        __syncthreads();                       // Khi ready
        if (kt + 1 < nkt) {                    // prefetch next tile (hides HBM)
#pragma unroll
            for (int ii = 0; ii < 4; ++ii)
                kpre[ii] = *(const f32x4*)&kB[(size_t)((kt + 1) * KT + sr + 16 * ii) * DIM + sc];
        }
        const int nmax = (kt == qb) ? (wave + 1) : 4;
        for (int n = 0; n < nmax; ++n) {
            bf16x8 kh0 = *(const bf16x8*)&Khi[(16 * n + lo) * KLD + hi * 8];
            bf16x8 kh1 = *(const bf16x8*)&Khi[(16 * n + lo) * KLD + 32 + hi * 8];
            f32x4 acc = {0.f, 0.f, 0.f, 0.f};
            acc = __builtin_amdgcn_mfma_f32_16x16x32_bf16(qa0h, kh0, acc, 0, 0, 0);
            acc = __builtin_amdgcn_mfma_f32_16x16x32_bf16(qa1h, kh1, acc, 0, 0, 0);
            if (kt < qb) {
#pragma unroll
                for (int jx = 0; jx < 4; ++jx) rl[jx] += __expf(acc[jx]);
            } else {
                const int col = 16 * n + lo;
#pragma unroll
                for (int jx = 0; jx < 4; ++jx)
                    if (col <= wave * 16 + hi * 4 + jx) rl[jx] += __expf(acc[jx]);
            }
        }
    }
#pragma unroll
    for (int m = 1; m <= 8; m <<= 1)
#pragma unroll
        for (int jx = 0; jx < 4; ++jx) rl[jx] += __shfl_xor(rl[jx], m, 16);
    float il[4];
#pragma unroll
    for (int jx = 0; jx < 4; ++jx) il[jx] = 1.0f / rl[jx];

    // ============ phase 2: P = exp(S)/l (fp32) + O = P*V ============
    f32x4 o[4];
#pragma unroll
    for (int n = 0; n < 4; ++n) { o[n][0] = 0.f; o[n][1] = 0.f; o[n][2] = 0.f; o[n][3] = 0.f; }

    f32x4 kp2[4], vp2[4];
#pragma unroll
    for (int ii = 0; ii < 4; ++ii) {
        kp2[ii] = *(const f32x4*)&kB[(size_t)(sr + 16 * ii) * DIM + sc];
        vp2[ii] = *(const f32x4*)&vB[(size_t)(vr + ii) * DIM + sc];
    }

    for (int kt = 0; kt < nkt; ++kt) {
        __syncthreads();
        {   // stage K (split hi/lo) and V (transposed) from prefetched regs
#pragma unroll
            for (int ii = 0; ii < 4; ++ii) {
                short4v hh, ll;
#pragma unroll
                for (int e = 0; e < 4; ++e) {
                    short hb = f2bf(kp2[ii][e]);
                    hh[e] = hb; ll[e] = f2bf(kp2[ii][e] - bf2f(hb));
                }
                *(short4v*)&Khi[(sr + 16 * ii) * KLD + sc] = hh;
                *(short4v*)&Klo[(sr + 16 * ii) * KLD + sc] = ll;
            }
#pragma unroll
            for (int e = 0; e < 4; ++e) {      // 4x4 in-register transpose
                short4v tv;
#pragma unroll
                for (int ii = 0; ii < 4; ++ii) tv[ii] = f2bf(vp2[ii][e]);
                *(short4v*)&Vt[(sc + e) * VLD + vr] = tv;
            }
        }
        __syncthreads();
        if (kt + 1 < nkt) {                    // prefetch next K,V
#pragma unroll
            for (int ii = 0; ii < 4; ++ii) {
                kp2[ii] = *(const f32x4*)&kB[(size_t)((kt + 1) * KT + sr + 16 * ii) * DIM + sc];
                vp2[ii] = *(const f32x4*)&vB[(size_t)((kt + 1) * KT + vr + ii) * DIM + sc];
            }
        }
        // S = QK^T (compensated), P into fp32 LDS tile
#pragma unroll
        for (int n = 0; n < 4; ++n) {
            const bool fm = (kt == qb) && (n > wave);  // wave-uniform
            f32x4 acc = {0.f, 0.f, 0.f, 0.f};
            if (!fm) {
                bf16x8 kh0 = *(const bf16x8*)&Khi[(16 * n + lo) * KLD + hi * 8];
                bf16x8 kh1 = *(const bf16x8*)&Khi[(16 * n + lo) * KLD + 32 + hi * 8];
                bf16x8 kl0 = *(const bf16x8*)&Klo[(16 * n + lo) * KLD + hi * 8];
                bf16x8 kl1 = *(const bf16x8*)&Klo[(16 * n + lo) * KLD + 32 + hi * 8];
                acc = __builtin_amdgcn_mfma_f32_16x16x32_bf16(qa0h, kh0, acc, 0, 0, 0);
                acc = __builtin_amdgcn_mfma_f32_16x16x32_bf16(qa1h, kh1, acc, 0, 0, 0);
                acc = __builtin_amdgcn_mfma_f32_16x16x32_bf16(qa0h, kl0, acc, 0, 0, 0);
                acc = __builtin_amdgcn_mfma_f32_16x16x32_bf16(qa1h, kl1, acc, 0, 0, 0);
                acc = __builtin_amdgcn_mfma_f32_16x16x32_bf16(qa0l, kh0, acc, 0, 0, 0);
                acc = __builtin_amdgcn_mfma_f32_16x16x32_bf16(qa1l, kh1, acc, 0, 0, 0);
            }
            const int col = 16 * n + lo;
#pragma unroll
            for (int jx = 0; jx < 4; ++jx) {
                const int row = wave * 16 + hi * 4 + jx;
                const float p = (!fm && (kt < qb || col <= row)) ? __expf(acc[jx]) * il[jx] : 0.f;
                Pf[row * PFLD + col] = p;
            }
        }
        // stream own P band to global (issue stores before PV)
        {
            const int r = wave * 16 + (lane >> 2);
            const int cb = (lane & 3) * 16;
            float* dst = &Pg[((size_t)(b * SEQ) + q0 + r) * SEQ + kt * KT + cb];
            const float* src = &Pf[r * PFLD + cb];
#pragma unroll
            for (int iw = 0; iw < 4; ++iw)
                *(f32x4*)&dst[4 * iw] = *(const f32x4*)&src[4 * iw];
        }
        // PV: A-frag from own Pf band (fp32->bf16), B-frag from Vt
        {
            const float* pr = &Pf[(wave * 16 + lo) * PFLD + hi * 8];
            bf16x8 pa0, pa1;
            {
                f32x4 a = *(const f32x4*)pr, c2 = *(const f32x4*)(pr + 4);
                f32x4 d = *(const f32x4*)(pr + 32), e2 = *(const f32x4*)(pr + 36);
#pragma unroll
                for (int e = 0; e < 4; ++e) {
                    pa0[e] = f2bf(a[e]); pa0[4 + e] = f2bf(c2[e]);
                    pa1[e] = f2bf(d[e]); pa1[4 + e] = f2bf(e2[e]);
                }
            }
#pragma unroll
            for (int n = 0; n < 4; ++n) {
                bf16x8 vb0 = *(const bf16x8*)&Vt[(16 * n + lo) * VLD + hi * 8];
                bf16x8 vb1 = *(const bf16x8*)&Vt[(16 * n + lo) * VLD + 32 + hi * 8];
                o[n] = __builtin_amdgcn_mfma_f32_16x16x32_bf16(pa0, vb0, o[n], 0, 0, 0);
                o[n] = __builtin_amdgcn_mfma_f32_16x16x32_bf16(pa1, vb1, o[n], 0, 0, 0);
            }
        }
    }

    // ---- zero-fill fully-masked column tiles (exact 0 == ref underflow) ----
    {
        const int r = tid >> 2;
        float* rowp = &Pg[((size_t)(b * SEQ) + q0 + r) * SEQ];
        const f32x4 z = {0.f, 0.f, 0.f, 0.f};
        for (int cb = nkt * KT + (tid & 3) * 16; cb < SEQ; cb += KT)
#pragma unroll
            for (int iw = 0; iw < 4; ++iw)
                *(f32x4*)&rowp[cb + 4 * iw] = z;
    }
    // ---- O (already normalized), fp32 ----
    {
        float* og = &Og[((size_t)(b * SEQ) + q0 + wave * 16 + hi * 4) * DIM + lo];
#pragma unroll
        for (int jx = 0; jx < 4; ++jx)
#pragma unroll
            for (int n = 0; n < 4; ++n)
                og[jx * DIM + n * 16] = o[n][jx];
    }
}

extern "C" void kernel_launch(void* const* d_in, const int* in_sizes, int n_in,
                              void* d_out, int out_size, void* d_ws, size_t ws_size,
                              hipStream_t stream) {
    const float* q = (const float*)d_in[0];
    const float* k = (const float*)d_in[1];
    const float* v = (const float*)d_in[2];
    float* out  = (float*)d_out;                        // [B,T,D] fp32
    float* smqk = out + (size_t)BATCHES * SEQ * DIM;    // [B,T,T] fp32

    sdpa_fused<<<NQB * BATCHES, 256, 0, stream>>>(q, k, v, out, smqk);
}